// Round 17
// baseline (35.933 us; speedup 1.0000x reference)
//
#include <hip/hip_runtime.h>
#include <math.h>

#define NL 28
#define H 1024
#define W 1024
#define HW (H * W)
#define BROW 1152         // padded mask row: 64 guard | 1024 data | 64 guard
#define GUARD 64
#define NP 5              // passes per wave (wave0: 0-4, wave1: 5-9; 9 real)

// Naturally-aligned 8B vector -> ds_read_b64 / global f2 ops. Safe: fast
// path gated on "all dx even" (so every address is base+even_float).
typedef float f2 __attribute__((ext_vector_type(2)));

typedef __attribute__((address_space(1))) const void GV;
typedef __attribute__((address_space(3))) void LV;
__device__ __forceinline__ void gl_lds16(const float* g, float* l) {
    __builtin_amdgcn_global_load_lds((GV*)g, (LV*)l, 16, 0, 0);
}

// out[Y,X] = sum_l mask[Y-dy_l, X-dx_l] * x[l, Y-dy_l, X-dx_l]
// v17: x is read-once data -> NO LDS staging for x (v8-v16 staged it for
// zero reuse). Only the mask (28x reuse across bands) lives in LDS (2
// guard-padded rows, 9.2 KB). Per band: 5 coalesced global f2 loads
// (med3-clamped cols; zeroed mask guards kill OOB) + 5 ds_read_b64 + 5 FMA.
// One barrier total. Halves LDS traffic, removes the vmcnt choreography.
__global__ __launch_bounds__(128)
void cassi_v17(const float* __restrict__ x, const float* __restrict__ mask,
               const float* __restrict__ phi_deg, const float* __restrict__ s_nom,
               float* __restrict__ out, int out_size)
{
    __shared__ float mb[2 * BROW];  // mask rows Y, Y-1 (guarded) = 9.2 KB

    const int tid = threadIdx.x;
    const int lane = tid & 63;
    const int wid = tid >> 6;

    // ---- offsets: computed redundantly by every wave ----
    float phi = phi_deg[0] * 0.017453292519943295f;
    float c = cosf(phi), sn = sinf(phi);
    float s = (lane < NL) ? s_nom[lane] : 0.f;
    float dxv = s * c, dyv = s * sn;
    float dxm = (lane < NL) ? dxv : 3.0e38f;
    float dym = (lane < NL) ? dyv : 3.0e38f;
    for (int d = 1; d < 64; d <<= 1) {
        dxm = fminf(dxm, __shfl_xor(dxm, d, 64));
        dym = fminf(dym, __shfl_xor(dym, d, 64));
    }
    int dxi = (lane < NL) ? (int)rintf(dxv - dxm) : 0;
    int dyi = (lane < NL) ? (int)rintf(dyv - dym) : 0;
    int dxmax = dxi, dymax = dyi, dxodd = dxi & 1;
    for (int d = 1; d < 64; d <<= 1) {
        dxmax = max(dxmax, __shfl_xor(dxmax, d, 64));
        dymax = max(dymax, __shfl_xor(dymax, d, 64));
        dxodd = max(dxodd, __shfl_xor(dxodd, d, 64));  // OR: any odd dx?
    }
    const int Wp = W + dxmax;
    const int Hp = out_size / Wp;

    if (!(dymax <= 1 && dxmax <= GUARD && dxodd == 0)) {
        // Self-contained checked fallback (never taken for bench geometry).
        for (int i = blockIdx.x * 128 + tid; i < out_size; i += gridDim.x * 128) {
            int Yk = i / Wp, Xk = i - Yk * Wp;
            float a = 0.f;
            for (int l = 0; l < NL; ++l) {
                float sl = s_nom[l];
                int dx = (int)rintf(sl * c - dxm);
                int dy = (int)rintf(sl * sn - dym);
                int h = Yk - dy, w = Xk - dx;
                if ((unsigned)h < (unsigned)H && (unsigned)w < (unsigned)W) {
                    int p = h * W + w;
                    a = fmaf(mask[p], x[(size_t)l * HW + p], a);
                }
            }
            out[i] = a;
        }
        return;
    }

    const int Y = blockIdx.x;
    if (Y >= Hp) return;  // uniform exit before the barrier

    // ---- stage mask row (wave wid -> row Y-wid), guard-padded ----
    {
        int g = Y - wid;
        float* mrow = &mb[wid * BROW];
        if ((unsigned)g < (unsigned)H) {
            const float* src = mask + (size_t)g * W + lane * 4;
            gl_lds16(src,       mrow + GUARD);
            gl_lds16(src + 256, mrow + GUARD + 256);
            gl_lds16(src + 512, mrow + GUARD + 512);
            gl_lds16(src + 768, mrow + GUARD + 768);
            mrow[lane] = 0.f;
            mrow[GUARD + 1024 + lane] = 0.f;
        } else {
            for (int k = lane; k < BROW; k += 64) mrow[k] = 0.f;
        }
    }
    asm volatile("s_waitcnt vmcnt(0) lgkmcnt(0)" ::: "memory");
    __builtin_amdgcn_s_barrier();   // the ONLY barrier (both mask rows ready)

    // Per-wave half row: wave0 passes 0-4, wave1 passes 5-9 (pass 9 is a
    // phantom: te clamps to 0, store is guarded off).
    int te[NP];
    f2 acc[NP];
#pragma unroll
    for (int p = 0; p < NP; ++p) {
        int t = (wid * NP + p) * 128 + 2 * lane;
        te[p] = (t < Wp) ? t : 0;
        acc[p] = f2{0.f, 0.f};
    }

    // ---- band loop: 5 global f2 + 5 ds_read_b64 + 5 FMA per band ----
#pragma unroll
    for (int l = 0; l < NL; ++l) {
        int dxl = __shfl(dxi, l, 64);
        int dyl = __shfl(dyi, l, 64);
        int row = min(max(Y - dyl, 0), H - 1);   // clamp; zero mask row kills OOB
        const float* xrow = x + (size_t)l * HW + (size_t)row * W;
        const float* mrow = mb + dyl * BROW + GUARD - dxl;

        f2 xv[NP], mv[NP];
#pragma unroll
        for (int p = 0; p < NP; ++p) {
            // Clamped col (even->even: 8B alignment holds); OOB cols get
            // in-buffer values that the zeroed mask guards annihilate.
            int off = min(max(te[p] - dxl, 0), W - 2);
            xv[p] = *(const f2*)(xrow + off);     // coalesced 512B/wave
            mv[p] = *(const f2*)&mrow[te[p]];     // ds_read_b64
        }
#pragma unroll
        for (int p = 0; p < NP; ++p) acc[p] += mv[p] * xv[p];
    }

    // ---- store own half row ----
    float* orow = out + (size_t)Y * Wp;  // Wp even -> 8B-aligned f2 stores
#pragma unroll
    for (int p = 0; p < NP; ++p) {
        int t = (wid * NP + p) * 128 + 2 * lane;
        if (t + 1 < Wp)  *(f2*)&orow[t] = acc[p];
        else if (t < Wp) orow[t] = acc[p].x;
    }
}

extern "C" void kernel_launch(void* const* d_in, const int* in_sizes, int n_in,
                              void* d_out, int out_size, void* d_ws, size_t ws_size,
                              hipStream_t stream) {
    const float* x = (const float*)d_in[0];      // [1, 28, 1024, 1024]
    const float* mask = (const float*)d_in[1];   // [1024, 1024]
    const float* phi = (const float*)d_in[2];    // [1]
    const float* s_nom = (const float*)d_in[3];  // [28]
    float* out = (float*)d_out;                  // [1, Hp, Wp]

    // One block per output row; Hp <= out_size/W (since Wp >= W).
    const int blocks = out_size / W + 2;
    cassi_v17<<<blocks, 128, 0, stream>>>(x, mask, phi, s_nom, out, out_size);
}